// Round 1
// baseline (542.996 us; speedup 1.0000x reference)
//
#include <hip/hip_runtime.h>
#include <hip/hip_bf16.h>

typedef unsigned short u16;
typedef __attribute__((ext_vector_type(8))) short bf16x8;  // 8 bf16 = 4 VGPRs
typedef __attribute__((ext_vector_type(4))) float f32x4;

#define BB 4
#define CC 512
#define NN 4096

// ---------------------------------------------------------------------------
// prep: x fp32 [B][C][N] -> XT bf16 [B][N][C] (transposed) and XN bf16 [B][C][N]
// ---------------------------------------------------------------------------
__global__ __launch_bounds__(256) void prep_kernel(const float* __restrict__ x,
                                                   u16* __restrict__ XT,
                                                   u16* __restrict__ XN) {
    __shared__ u16 tile[64][65];          // +1 pad breaks bank conflicts
    int blk = blockIdx.x;                  // 4 * 8 * 64 = 2048 blocks
    int b  = blk >> 9;                     // 512 blocks per batch
    int r2 = blk & 511;
    int c0 = (r2 >> 6) << 6;               // 8 c-tiles of 64
    int n0 = (r2 & 63) << 6;               // 64 n-tiles of 64
    int t  = threadIdx.x;
    int qt = t >> 6;                       // 0..3
    int ln = t & 63;                       // 0..63
    #pragma unroll
    for (int rr = 0; rr < 16; ++rr) {
        int cc = rr * 4 + qt;              // 0..63
        float v = x[((size_t)(b * CC + c0 + cc) * NN) + n0 + ln];
        __hip_bfloat16 h = __float2bfloat16(v);
        u16 u = *(u16*)&h;
        XN[((size_t)(b * CC + c0 + cc) * NN) + n0 + ln] = u;
        tile[cc][ln] = u;
    }
    __syncthreads();
    #pragma unroll
    for (int rr = 0; rr < 16; ++rr) {
        int nn2 = rr * 4 + qt;
        XT[((size_t)(b * NN + n0 + nn2) * CC) + c0 + ln] = tile[ln][nn2];
    }
}

// ---------------------------------------------------------------------------
// flash attention: per block: batch b, 64 query rows. Iterate 128 key tiles of
// 32. GEMM1 (S = Q Kt^T) from LDS-staged transposed K-tile; GEMM2 as
// O^T = V P^T with V fragments read directly from global XN (L2-resident) and
// P^T from LDS. Online softmax state per wave (16 rows each).
// ---------------------------------------------------------------------------
__global__ __launch_bounds__(256, 1) void flash_kernel(const u16* __restrict__ XT,
                                                       const u16* __restrict__ XN,
                                                       float* __restrict__ out) {
    // K-tile transposed: [j 0..31][c 0..511], row stride 520 (16B aligned, pads banks)
    __shared__ __align__(16) u16 KtT[32 * 520];           // 33280 B
    __shared__ __align__(16) u16 Plds[2][64 * 40];        // P double buffer, row stride 40
    __shared__ float aLds[2][64];                          // alpha by row, double buffered
    __shared__ float lLds[64];

    int blk = blockIdx.x;            // 256 blocks
    int xcd = blk & 7;               // XCD-aware: batch pinned to XCD pair -> K stays in L2
    int b   = xcd >> 1;              // 0..3
    int ib  = (blk >> 3) + ((xcd & 1) << 5);   // 0..63
    int i_base = ib * 64;

    int t    = threadIdx.x;
    int w    = t >> 6;               // wave 0..3
    int lane = t & 63;
    int l15  = lane & 15;
    int q    = lane >> 4;            // quad 0..3

    // Q fragments (A-operand, rows i_base + w*16 + l15): 16 k-chunks of 32 c
    bf16x8 qf[16];
    {
        const u16* qrow = XT + (size_t)(b * NN + i_base + w * 16 + l15) * CC;
        #pragma unroll
        for (int kk = 0; kk < 16; ++kk)
            qf[kk] = *(const bf16x8*)(qrow + kk * 32 + q * 8);
    }

    // O^T accumulator: wave owns c in [w*128, w*128+128): 8 c-tiles x 4 i-tiles
    f32x4 o[8][4];
    #pragma unroll
    for (int ct = 0; ct < 8; ++ct)
        #pragma unroll
        for (int it = 0; it < 4; ++it)
            o[ct][it] = (f32x4){0.f, 0.f, 0.f, 0.f};

    float m_i[4], l_i[4];            // softmax state for rows q*4 + r (dup across 16 lanes)
    #pragma unroll
    for (int r = 0; r < 4; ++r) { m_i[r] = -INFINITY; l_i[r] = 0.f; }

    const u16* xnb = XN + (size_t)b * CC * NN;

    for (int jt0 = 0; jt0 < 128; ++jt0) {
        int j0  = jt0 * 32;
        int buf = jt0 & 1;

        // ---- stage KtT[j][c] (32 x 512 bf16) from XT rows j0..j0+31
        {
            int jr  = t >> 3;        // 0..31
            int ch0 = t & 7;         // 0..7
            const u16* src = XT + (size_t)(b * NN + j0 + jr) * CC;
            #pragma unroll
            for (int u = 0; u < 8; ++u) {
                int ch = ch0 + u * 8;
                *(bf16x8*)&KtT[jr * 520 + ch * 8] = *(const bf16x8*)(src + ch * 8);
            }
        }
        __syncthreads();

        // ---- GEMM1: S[16 rows of this wave][32 j]
        f32x4 s0 = {0.f,0.f,0.f,0.f}, s1 = {0.f,0.f,0.f,0.f};
        #pragma unroll
        for (int kk = 0; kk < 16; ++kk) {
            bf16x8 b0 = *(const bf16x8*)&KtT[(l15)      * 520 + kk * 32 + q * 8];
            bf16x8 b1 = *(const bf16x8*)&KtT[(16 + l15) * 520 + kk * 32 + q * 8];
            s0 = __builtin_amdgcn_mfma_f32_16x16x32_bf16(qf[kk], b0, s0, 0, 0, 0);
            s1 = __builtin_amdgcn_mfma_f32_16x16x32_bf16(qf[kk], b1, s1, 0, 0, 0);
        }

        // ---- online softmax, rows q*4+r; cols spread over l15 (reduce via shfl_xor)
        #pragma unroll
        for (int r = 0; r < 4; ++r) {
            float mt = fmaxf(s0[r], s1[r]);
            mt = fmaxf(mt, __shfl_xor(mt, 1));
            mt = fmaxf(mt, __shfl_xor(mt, 2));
            mt = fmaxf(mt, __shfl_xor(mt, 4));
            mt = fmaxf(mt, __shfl_xor(mt, 8));
            float mnew  = fmaxf(m_i[r], mt);
            float alpha = __expf(m_i[r] - mnew);   // 0 on first iter (m = -inf)
            float p0 = __expf(s0[r] - mnew);
            float p1 = __expf(s1[r] - mnew);
            float sum = p0 + p1;
            sum += __shfl_xor(sum, 1);
            sum += __shfl_xor(sum, 2);
            sum += __shfl_xor(sum, 4);
            sum += __shfl_xor(sum, 8);
            l_i[r] = l_i[r] * alpha + sum;
            m_i[r] = mnew;
            int row = w * 16 + q * 4 + r;
            // bf16 truncation: P in [0,1], 1.0 stays exact; error << threshold
            Plds[buf][row * 40 +      l15] = (u16)(__builtin_bit_cast(unsigned int, p0) >> 16);
            Plds[buf][row * 40 + 16 + l15] = (u16)(__builtin_bit_cast(unsigned int, p1) >> 16);
            if (l15 == 0) aLds[buf][row] = alpha;
        }
        __syncthreads();

        // ---- GEMM2: O^T[c][i] = alpha*O^T + V*P^T   (V = K tile, from global XN)
        bf16x8 pb[4];
        float  av[4];
        #pragma unroll
        for (int it = 0; it < 4; ++it) {
            pb[it] = *(const bf16x8*)&Plds[buf][(it * 16 + l15) * 40 + q * 8];
            av[it] = aLds[buf][it * 16 + l15];
        }
        bool need = (av[0] != 1.f) | (av[1] != 1.f) | (av[2] != 1.f) | (av[3] != 1.f);
        if (__any(need)) {           // skip 128 muls when max didn't move (common case)
            #pragma unroll
            for (int ct = 0; ct < 8; ++ct)
                #pragma unroll
                for (int it = 0; it < 4; ++it)
                    o[ct][it] *= av[it];
        }
        #pragma unroll
        for (int ct = 0; ct < 8; ++ct) {
            const u16* arow = xnb + (size_t)(w * 128 + ct * 16 + l15) * NN + j0 + q * 8;
            bf16x8 af = *(const bf16x8*)arow;
            #pragma unroll
            for (int it = 0; it < 4; ++it)
                o[ct][it] = __builtin_amdgcn_mfma_f32_16x16x32_bf16(af, pb[it], o[ct][it], 0, 0, 0);
        }
        // no end barrier: KtT overwrite is safe after the post-softmax barrier,
        // P/alpha are double-buffered
    }

    // ---- epilogue: divide by l (indexed by column i) and store fp32
    if (l15 == 0) {
        #pragma unroll
        for (int r = 0; r < 4; ++r) lLds[w * 16 + q * 4 + r] = l_i[r];
    }
    __syncthreads();
    float linv[4];
    #pragma unroll
    for (int it = 0; it < 4; ++it) linv[it] = 1.f / lLds[it * 16 + l15];

    float* ob = out + (size_t)b * CC * NN;
    #pragma unroll
    for (int ct = 0; ct < 8; ++ct) {
        #pragma unroll
        for (int r = 0; r < 4; ++r) {
            int c = w * 128 + ct * 16 + q * 4 + r;
            float* orow = ob + (size_t)c * NN + i_base;
            #pragma unroll
            for (int it = 0; it < 4; ++it)
                orow[it * 16 + l15] = o[ct][it][r] * linv[it];
        }
    }
}

extern "C" void kernel_launch(void* const* d_in, const int* in_sizes, int n_in,
                              void* d_out, int out_size, void* d_ws, size_t ws_size,
                              hipStream_t stream) {
    const float* x = (const float*)d_in[0];
    u16* XT = (u16*)d_ws;                          // 16 MiB
    u16* XN = XT + (size_t)BB * NN * CC;           // next 16 MiB
    float* out = (float*)d_out;
    prep_kernel<<<2048, 256, 0, stream>>>(x, XT, XN);
    flash_kernel<<<256, 256, 0, stream>>>(XT, XN, out);
}

// Round 2
// 460.132 us; speedup vs baseline: 1.1801x; 1.1801x over previous
//
#include <hip/hip_runtime.h>
#include <hip/hip_bf16.h>

typedef unsigned short u16;
typedef unsigned int   u32;
typedef unsigned long long u64;
typedef __attribute__((ext_vector_type(8))) short bf16x8;  // 8 bf16 = 4 VGPRs
typedef __attribute__((ext_vector_type(4))) float f32x4;

#define BB 4
#define CC 512
#define NN 4096

__device__ __forceinline__ u16 f2b(float f) {
    __hip_bfloat16 h = __float2bfloat16(f);
    return *(u16*)&h;
}

// async global -> LDS, 16B per lane, wave-uniform LDS base + lane*16
typedef __attribute__((address_space(1))) const u32 GU32;
typedef __attribute__((address_space(3))) u32 LU32;
__device__ __forceinline__ void async16(const void* g, void* l) {
    __builtin_amdgcn_global_load_lds((GU32*)g, (LU32*)l, 16, 0, 0);
}

// ---------------------------------------------------------------------------
// prep: x fp32 [B][C][N] -> XT bf16 [B][N][C] and XN bf16 [B][C][N]
// ---------------------------------------------------------------------------
__global__ __launch_bounds__(256) void prep_kernel(const float* __restrict__ x,
                                                   u16* __restrict__ XT,
                                                   u16* __restrict__ XN) {
    __shared__ __align__(8) u16 tile[64][68];   // stride 68: rows 8B-aligned, bank-skewed
    int blk = blockIdx.x;                  // 2048 blocks
    int b  = blk >> 9;
    int r2 = blk & 511;
    int c0 = (r2 >> 6) << 6;
    int n0 = (r2 & 63) << 6;
    int t  = threadIdx.x;

    int nq    = t & 15;                    // float4 index along n
    int rbase = t >> 4;                    // 0..15
    #pragma unroll
    for (int p = 0; p < 4; ++p) {
        int cl = p * 16 + rbase;
        const float* src = x + ((size_t)(b * CC + c0 + cl) * NN) + n0 + nq * 4;
        float4 v = *(const float4*)src;
        u64 pk = (u64)f2b(v.x) | ((u64)f2b(v.y) << 16) |
                 ((u64)f2b(v.z) << 32) | ((u64)f2b(v.w) << 48);
        *(u64*)&XN[((size_t)(b * CC + c0 + cl) * NN) + n0 + nq * 4] = pk;
        *(u64*)&tile[cl][nq * 4] = pk;
    }
    __syncthreads();
    int c2 = (t & 31) * 2;
    int nb = t >> 5;                       // 0..7
    #pragma unroll
    for (int rr = 0; rr < 8; ++rr) {
        int nl = rr * 8 + nb;
        u32 lo = tile[c2][nl], hi = tile[c2 + 1][nl];
        *(u32*)&XT[((size_t)(b * NN + n0 + nl) * CC) + c0 + c2] = lo | (hi << 16);
    }
}

// ---------------------------------------------------------------------------
// flash attention over key range [jlo, jlo+2048) (split) or full (fallback).
// Per block: 64 query rows, 4 waves. GEMM1 S = Q K^T from async-staged LDS
// K-tile; GEMM2 O^T += V P^T with V fragments register-prefetched from XN.
// ---------------------------------------------------------------------------
__global__ __launch_bounds__(256, 2) void flash_kernel(const u16* __restrict__ XT,
                                                       const u16* __restrict__ XN,
                                                       float* __restrict__ outF,
                                                       u16* __restrict__ outH,
                                                       float2* __restrict__ ml0,
                                                       float2* __restrict__ ml1,
                                                       int split) {
    __shared__ __align__(16) u16 KtT[32 * 520];           // [j][c], stride 520
    __shared__ __align__(16) u16 Plds[2][64 * 40];        // P double buffer
    __shared__ float aLds[2][64];
    __shared__ float lLds[64];

    int blk   = blockIdx.x;
    int inner = blk & 255;
    int hf    = split ? (blk >> 8) : 0;       // key half
    int xcd = inner & 7;
    int b   = xcd >> 1;
    int ib  = (inner >> 3) + ((xcd & 1) << 5);
    int i_base = ib * 64;
    int jlo = hf * (NN / 2) * split;
    int njt = split ? 64 : 128;

    int t    = threadIdx.x;
    int w    = t >> 6;
    int lane = t & 63;
    int l15  = lane & 15;
    int q    = lane >> 4;

    // Q fragments: rows i_base + w*16 + l15, all 512 c (16 k-chunks)
    bf16x8 qf[16];
    {
        const u16* qrow = XT + (size_t)(b * NN + i_base + w * 16 + l15) * CC;
        #pragma unroll
        for (int kk = 0; kk < 16; ++kk)
            qf[kk] = *(const bf16x8*)(qrow + kk * 32 + q * 8);
    }

    f32x4 o[8][4];
    #pragma unroll
    for (int ct = 0; ct < 8; ++ct)
        #pragma unroll
        for (int it = 0; it < 4; ++it)
            o[ct][it] = (f32x4){0.f, 0.f, 0.f, 0.f};

    float m_i[4], l_i[4];
    #pragma unroll
    for (int r = 0; r < 4; ++r) { m_i[r] = -INFINITY; l_i[r] = 0.f; }

    const u16* xnb = XN + (size_t)b * CC * NN;

    for (int jt = 0; jt < njt; ++jt) {
        int j0  = jlo + jt * 32;
        int buf = jt & 1;

        // ---- async stage KtT rows: wave w stages rows w*8 .. w*8+8
        {
            const u16* src = XT + (size_t)(b * NN + j0 + w * 8) * CC + lane * 8;
            #pragma unroll
            for (int rr = 0; rr < 8; ++rr)
                async16(src + rr * CC, &KtT[(w * 8 + rr) * 520]);
        }
        // ---- V-fragment register prefetch (consumed in GEMM2)
        bf16x8 vf[8];
        #pragma unroll
        for (int ct = 0; ct < 8; ++ct)
            vf[ct] = *(const bf16x8*)(xnb + (size_t)(w * 128 + ct * 16 + l15) * NN + j0 + q * 8);

        __syncthreads();   // drains staging + prefetch

        // ---- GEMM1: S[16 rows][32 j]
        f32x4 s0 = {0.f,0.f,0.f,0.f}, s1 = {0.f,0.f,0.f,0.f};
        #pragma unroll
        for (int kk = 0; kk < 16; ++kk) {
            bf16x8 b0 = *(const bf16x8*)&KtT[(l15)      * 520 + kk * 32 + q * 8];
            bf16x8 b1 = *(const bf16x8*)&KtT[(16 + l15) * 520 + kk * 32 + q * 8];
            s0 = __builtin_amdgcn_mfma_f32_16x16x32_bf16(qf[kk], b0, s0, 0, 0, 0);
            s1 = __builtin_amdgcn_mfma_f32_16x16x32_bf16(qf[kk], b1, s1, 0, 0, 0);
        }

        // ---- online softmax (rows q*4+r, cols over l15)
        #pragma unroll
        for (int r = 0; r < 4; ++r) {
            float mt = fmaxf(s0[r], s1[r]);
            mt = fmaxf(mt, __shfl_xor(mt, 1));
            mt = fmaxf(mt, __shfl_xor(mt, 2));
            mt = fmaxf(mt, __shfl_xor(mt, 4));
            mt = fmaxf(mt, __shfl_xor(mt, 8));
            float mnew  = fmaxf(m_i[r], mt);
            float alpha = __expf(m_i[r] - mnew);
            float p0 = __expf(s0[r] - mnew);
            float p1 = __expf(s1[r] - mnew);
            float sum = p0 + p1;
            sum += __shfl_xor(sum, 1);
            sum += __shfl_xor(sum, 2);
            sum += __shfl_xor(sum, 4);
            sum += __shfl_xor(sum, 8);
            l_i[r] = l_i[r] * alpha + sum;
            m_i[r] = mnew;
            int row = w * 16 + q * 4 + r;
            Plds[buf][row * 40 +      l15] = (u16)(__builtin_bit_cast(u32, p0) >> 16);
            Plds[buf][row * 40 + 16 + l15] = (u16)(__builtin_bit_cast(u32, p1) >> 16);
            if (l15 == 0) aLds[buf][row] = alpha;
        }
        __syncthreads();

        // ---- GEMM2: O^T = alpha*O^T + V P^T
        bf16x8 pb[4];
        float  av[4];
        #pragma unroll
        for (int it = 0; it < 4; ++it) {
            pb[it] = *(const bf16x8*)&Plds[buf][(it * 16 + l15) * 40 + q * 8];
            av[it] = aLds[buf][it * 16 + l15];
        }
        bool need = (av[0] != 1.f) | (av[1] != 1.f) | (av[2] != 1.f) | (av[3] != 1.f);
        if (__any(need)) {
            #pragma unroll
            for (int ct = 0; ct < 8; ++ct)
                #pragma unroll
                for (int it = 0; it < 4; ++it)
                    o[ct][it] *= av[it];
        }
        #pragma unroll
        for (int ct = 0; ct < 8; ++ct) {
            #pragma unroll
            for (int it = 0; it < 4; ++it)
                o[ct][it] = __builtin_amdgcn_mfma_f32_16x16x32_bf16(vf[ct], pb[it], o[ct][it], 0, 0, 0);
        }
    }

    // ---- epilogue
    if (!split) {
        if (l15 == 0) {
            #pragma unroll
            for (int r = 0; r < 4; ++r) lLds[w * 16 + q * 4 + r] = l_i[r];
        }
        __syncthreads();
        float linv[4];
        #pragma unroll
        for (int it = 0; it < 4; ++it) linv[it] = 1.f / lLds[it * 16 + l15];
        float* ob = outF + (size_t)b * CC * NN;
        #pragma unroll
        for (int ct = 0; ct < 8; ++ct)
            #pragma unroll
            for (int r = 0; r < 4; ++r) {
                int c = w * 128 + ct * 16 + q * 4 + r;
                float* orow = ob + (size_t)c * NN + i_base;
                #pragma unroll
                for (int it = 0; it < 4; ++it)
                    orow[it * 16 + l15] = o[ct][it][r] * linv[it];
            }
    } else {
        if (l15 == 0) {
            float2* mlp = (hf == 0) ? ml0 : ml1;
            #pragma unroll
            for (int r = 0; r < 4; ++r)
                mlp[(size_t)b * NN + i_base + w * 16 + q * 4 + r] =
                    make_float2(m_i[r], l_i[r]);
        }
        if (hf == 0) {
            float* ob = outF + (size_t)b * CC * NN;
            #pragma unroll
            for (int ct = 0; ct < 8; ++ct)
                #pragma unroll
                for (int r = 0; r < 4; ++r) {
                    int c = w * 128 + ct * 16 + q * 4 + r;
                    float* orow = ob + (size_t)c * NN + i_base;
                    #pragma unroll
                    for (int it = 0; it < 4; ++it)
                        orow[it * 16 + l15] = o[ct][it][r];    // unnormalized partial
                }
        } else {
            u16* ob = outH + (size_t)b * CC * NN;
            #pragma unroll
            for (int ct = 0; ct < 8; ++ct)
                #pragma unroll
                for (int r = 0; r < 4; ++r) {
                    int c = w * 128 + ct * 16 + q * 4 + r;
                    u16* orow = ob + (size_t)c * NN + i_base;
                    #pragma unroll
                    for (int it = 0; it < 4; ++it)
                        orow[it * 16 + l15] = f2b(o[ct][it][r]);
                }
        }
    }
}

// ---------------------------------------------------------------------------
// combine: out = (w0*P0 + w1*P1) / (w0*l0 + w1*l1), w_h = e^{m_h - max}
// ---------------------------------------------------------------------------
__global__ __launch_bounds__(256) void combine_kernel(float* __restrict__ out,
                                                      const u16* __restrict__ P1,
                                                      const float2* __restrict__ ml0,
                                                      const float2* __restrict__ ml1) {
    size_t g = (size_t)blockIdx.x * 256 + threadIdx.x;
    size_t f = g * 4;
    int i = (int)(f & (NN - 1));
    int b = (int)(f >> 21);                 // / (CC*NN) = 2^21
    const float2* a0 = ml0 + (size_t)b * NN + i;
    const float2* a1 = ml1 + (size_t)b * NN + i;
    float4 p0 = *(float4*)&out[f];
    u64 pk = *(const u64*)&P1[f];
    float p0a[4] = {p0.x, p0.y, p0.z, p0.w};
    float r[4];
    #pragma unroll
    for (int k = 0; k < 4; ++k) {
        float2 A = a0[k], B = a1[k];
        float m  = fmaxf(A.x, B.x);
        float w0 = __expf(A.x - m), w1 = __expf(B.x - m);
        float l  = w0 * A.y + w1 * B.y;
        u32 pb   = (u32)((pk >> (16 * k)) & 0xFFFFu) << 16;
        float p1f = __builtin_bit_cast(float, pb);
        r[k] = (w0 * p0a[k] + w1 * p1f) / l;
    }
    *(float4*)&out[f] = (float4){r[0], r[1], r[2], r[3]};
}

extern "C" void kernel_launch(void* const* d_in, const int* in_sizes, int n_in,
                              void* d_out, int out_size, void* d_ws, size_t ws_size,
                              hipStream_t stream) {
    const float* x = (const float*)d_in[0];
    size_t SZ = (size_t)BB * NN * CC;          // elements
    u16* XT = (u16*)d_ws;
    u16* XN = XT + SZ;
    u16* P1 = XN + SZ;
    float2* ml0 = (float2*)(P1 + SZ);
    float2* ml1 = ml0 + (size_t)BB * NN;
    size_t needed = 3 * SZ * 2 + 2 * (size_t)BB * NN * 8;
    int split = (ws_size >= needed) ? 1 : 0;
    float* out = (float*)d_out;

    prep_kernel<<<2048, 256, 0, stream>>>(x, XT, XN);
    if (split) {
        flash_kernel<<<512, 256, 0, stream>>>(XT, XN, out, P1, ml0, ml1, 1);
        combine_kernel<<<(BB * CC * NN / 4) / 256, 256, 0, stream>>>(out, P1, ml0, ml1);
    } else {
        flash_kernel<<<256, 256, 0, stream>>>(XT, XN, out, P1, ml0, ml1, 0);
    }
}

// Round 3
// 294.654 us; speedup vs baseline: 1.8428x; 1.5616x over previous
//
#include <hip/hip_runtime.h>
#include <hip/hip_bf16.h>

typedef unsigned short u16;
typedef unsigned int   u32;
typedef unsigned long long u64;
typedef __attribute__((ext_vector_type(8))) short bf16x8;  // 8 bf16 = 4 VGPRs
typedef __attribute__((ext_vector_type(4))) float f32x4;

#define BB 4
#define CC 512
#define NN 4096
#define LOG2E 1.44269504f

static __device__ __forceinline__ u16 f2b(float f) {
    __hip_bfloat16 h = __float2bfloat16(f);
    return *(u16*)&h;
}
static __device__ __forceinline__ u16 f2b_fast(float f) {   // round-half-up bf16
    u32 u = __builtin_bit_cast(u32, f);
    return (u16)((u + 0x8000u) >> 16);
}
static __device__ __forceinline__ float b2f(u16 b) {
    u32 u = (u32)b << 16;
    return __builtin_bit_cast(float, u);
}

// async global -> LDS, 16B per lane, wave-uniform LDS base + lane*16
typedef __attribute__((address_space(1))) const u32 GU32;
typedef __attribute__((address_space(3))) u32 LU32;
__device__ __forceinline__ void async16(const void* g, void* l) {
    __builtin_amdgcn_global_load_lds((GU32*)g, (LU32*)l, 16, 0, 0);
}

// ---------------------------------------------------------------------------
// prep: x fp32 [B][C][N] -> XT bf16 [B][N][C], XN bf16 [B][C][N],
//       norms[b][n] += sum_c x^2 (global atomics; norms pre-zeroed)
// ---------------------------------------------------------------------------
__global__ __launch_bounds__(256) void prep_kernel(const float* __restrict__ x,
                                                   u16* __restrict__ XT,
                                                   u16* __restrict__ XN,
                                                   float* __restrict__ norms) {
    __shared__ __align__(8) u16 tile[64][68];
    __shared__ float nsum[64];
    int blk = blockIdx.x;                  // 2048 blocks
    int b  = blk >> 9;
    int r2 = blk & 511;
    int c0 = (r2 >> 6) << 6;
    int n0 = (r2 & 63) << 6;
    int t  = threadIdx.x;
    if (t < 64) nsum[t] = 0.f;

    int nq    = t & 15;                    // float4 index along n
    int rbase = t >> 4;                    // 0..15
    float psum[4] = {0.f, 0.f, 0.f, 0.f};
    #pragma unroll
    for (int p = 0; p < 4; ++p) {
        int cl = p * 16 + rbase;
        const float* src = x + ((size_t)(b * CC + c0 + cl) * NN) + n0 + nq * 4;
        float4 v = *(const float4*)src;
        psum[0] += v.x * v.x; psum[1] += v.y * v.y;
        psum[2] += v.z * v.z; psum[3] += v.w * v.w;
        u64 pk = (u64)f2b(v.x) | ((u64)f2b(v.y) << 16) |
                 ((u64)f2b(v.z) << 32) | ((u64)f2b(v.w) << 48);
        *(u64*)&XN[((size_t)(b * CC + c0 + cl) * NN) + n0 + nq * 4] = pk;
        *(u64*)&tile[cl][nq * 4] = pk;
    }
    __syncthreads();                       // tile ready; nsum zero visible
    int c2 = (t & 31) * 2;
    int nb = t >> 5;
    #pragma unroll
    for (int rr = 0; rr < 8; ++rr) {
        int nl = rr * 8 + nb;
        u32 lo = tile[c2][nl], hi = tile[c2 + 1][nl];
        *(u32*)&XT[((size_t)(b * NN + n0 + nl) * CC) + c0 + c2] = lo | (hi << 16);
    }
    #pragma unroll
    for (int k = 0; k < 4; ++k) atomicAdd(&nsum[nq * 4 + k], psum[k]);
    __syncthreads();
    if (t < 64) atomicAdd(&norms[(size_t)b * NN + n0 + t], nsum[t]);
}

// max over norms per batch
__global__ __launch_bounds__(256) void maxn_kernel(const float* __restrict__ norms,
                                                   float* __restrict__ maxn) {
    int b = blockIdx.x, t = threadIdx.x;
    float m = 0.f;
    for (int k = t; k < NN; k += 256) m = fmaxf(m, norms[(size_t)b * NN + k]);
    #pragma unroll
    for (int d = 1; d < 64; d <<= 1) m = fmaxf(m, __shfl_xor(m, d));
    __shared__ float wred[4];
    if ((t & 63) == 0) wred[t >> 6] = m;
    __syncthreads();
    if (t == 0) maxn[b] = fmaxf(fmaxf(wred[0], wred[1]), fmaxf(wred[2], wred[3]));
}

// ---------------------------------------------------------------------------
// flash attention with STATIC per-row max bound M (no online rescale, no
// shuffles in the loop). One barrier per iteration: KtT double-buffered,
// stage(i+1) + V-register loads issued before GEMM1(i), drained at the
// single barrier after softmax.
// ---------------------------------------------------------------------------
__global__ __launch_bounds__(256, 2) void flash_kernel(const u16* __restrict__ XT,
                                                       const u16* __restrict__ XN,
                                                       const float* __restrict__ norms,
                                                       const float* __restrict__ maxn,
                                                       float* __restrict__ outF,
                                                       u16* __restrict__ outH,
                                                       float* __restrict__ l0g,
                                                       float* __restrict__ l1g,
                                                       int split) {
    __shared__ __align__(16) u16 KtT[2][32 * 520];        // [j][c], stride 520
    __shared__ __align__(16) u16 Plds[2][64 * 40];
    __shared__ float lLds[64];

    int blk   = blockIdx.x;
    int inner = blk & 255;
    int hf    = split ? (blk >> 8) : 0;
    int xcd = inner & 7;
    int b   = xcd >> 1;
    int ib  = (inner >> 3) + ((xcd & 1) << 5);
    int i_base = ib * 64;
    int jlo = hf * (NN / 2) * split;
    int njt = split ? 64 : 128;

    int t    = threadIdx.x;
    int w    = t >> 6;
    int lane = t & 63;
    int l15  = lane & 15;
    int q    = lane >> 4;

    const u16* xtb = XT + (size_t)b * NN * CC;
    const u16* xnb = XN + (size_t)b * CC * NN;

    // per-row static max bound, pre-scaled by log2e
    float mxn = maxn[b];
    float M2[4];
    #pragma unroll
    for (int r = 0; r < 4; ++r) {
        float nr = norms[(size_t)b * NN + i_base + w * 16 + q * 4 + r];
        M2[r] = (sqrtf(nr * mxn) - 40.f) * LOG2E;
    }

    // Q fragments: rows i_base + w*16 + l15, all 512 c
    bf16x8 qf[16];
    {
        const u16* qrow = xtb + (size_t)(i_base + w * 16 + l15) * CC;
        #pragma unroll
        for (int kk = 0; kk < 16; ++kk)
            qf[kk] = *(const bf16x8*)(qrow + kk * 32 + q * 8);
    }

    f32x4 o[8][4];
    #pragma unroll
    for (int ct = 0; ct < 8; ++ct)
        #pragma unroll
        for (int it = 0; it < 4; ++it)
            o[ct][it] = (f32x4){0.f, 0.f, 0.f, 0.f};
    float lpart[4] = {0.f, 0.f, 0.f, 0.f};

    // prologue: stage tile 0
    {
        const u16* src = xtb + (size_t)(jlo + w * 8) * CC + lane * 8;
        #pragma unroll
        for (int rr = 0; rr < 8; ++rr)
            async16(src + rr * CC, &KtT[0][(w * 8 + rr) * 520]);
    }
    __syncthreads();

    for (int jt = 0; jt < njt; ++jt) {
        int buf = jt & 1;
        int j0  = jlo + jt * 32;

        // V fragments for THIS iter (drained at the barrier below)
        bf16x8 vf[8];
        #pragma unroll
        for (int ct = 0; ct < 8; ++ct)
            vf[ct] = *(const bf16x8*)(xnb + (size_t)(w * 128 + ct * 16 + l15) * NN + j0 + q * 8);

        // stage NEXT K-tile into the other buffer
        if (jt + 1 < njt) {
            const u16* src = xtb + (size_t)(j0 + 32 + w * 8) * CC + lane * 8;
            #pragma unroll
            for (int rr = 0; rr < 8; ++rr)
                async16(src + rr * CC, &KtT[buf ^ 1][(w * 8 + rr) * 520]);
        }

        // GEMM1: S[16 rows][32 j] from KtT[buf]
        f32x4 s0 = {0.f,0.f,0.f,0.f}, s1 = {0.f,0.f,0.f,0.f};
        #pragma unroll
        for (int kk = 0; kk < 16; ++kk) {
            bf16x8 b0 = *(const bf16x8*)&KtT[buf][(l15)      * 520 + kk * 32 + q * 8];
            bf16x8 b1 = *(const bf16x8*)&KtT[buf][(16 + l15) * 520 + kk * 32 + q * 8];
            s0 = __builtin_amdgcn_mfma_f32_16x16x32_bf16(qf[kk], b0, s0, 0, 0, 0);
            s1 = __builtin_amdgcn_mfma_f32_16x16x32_bf16(qf[kk], b1, s1, 0, 0, 0);
        }

        // softmax-lite: p = 2^(s*log2e - M2); no shuffles, no rescale
        #pragma unroll
        for (int r = 0; r < 4; ++r) {
            float p0 = __builtin_amdgcn_exp2f(fmaf(s0[r], LOG2E, -M2[r]));
            float p1 = __builtin_amdgcn_exp2f(fmaf(s1[r], LOG2E, -M2[r]));
            u16 h0 = f2b_fast(p0), h1 = f2b_fast(p1);
            lpart[r] += b2f(h0) + b2f(h1);       // l consistent with bf16 P
            int row = w * 16 + q * 4 + r;
            Plds[buf][row * 40 +      l15] = h0;
            Plds[buf][row * 40 + 16 + l15] = h1;
        }
        __syncthreads();   // drains vf + stage(i+1); P ready

        // GEMM2: O^T += V P^T (no alpha)
        bf16x8 pb[4];
        #pragma unroll
        for (int it = 0; it < 4; ++it)
            pb[it] = *(const bf16x8*)&Plds[buf][(it * 16 + l15) * 40 + q * 8];
        #pragma unroll
        for (int ct = 0; ct < 8; ++ct)
            #pragma unroll
            for (int it = 0; it < 4; ++it)
                o[ct][it] = __builtin_amdgcn_mfma_f32_16x16x32_bf16(vf[ct], pb[it], o[ct][it], 0, 0, 0);
    }

    // reduce l over the 16 column-lanes (once, not per-iter)
    #pragma unroll
    for (int r = 0; r < 4; ++r) {
        float s = lpart[r];
        s += __shfl_xor(s, 1);
        s += __shfl_xor(s, 2);
        s += __shfl_xor(s, 4);
        s += __shfl_xor(s, 8);
        lpart[r] = s;
    }

    if (!split) {
        if (l15 == 0) {
            #pragma unroll
            for (int r = 0; r < 4; ++r) lLds[w * 16 + q * 4 + r] = lpart[r];
        }
        __syncthreads();
        float linv[4];
        #pragma unroll
        for (int it = 0; it < 4; ++it) linv[it] = 1.f / lLds[it * 16 + l15];
        float* ob = outF + (size_t)b * CC * NN;
        #pragma unroll
        for (int ct = 0; ct < 8; ++ct)
            #pragma unroll
            for (int r = 0; r < 4; ++r) {
                int c = w * 128 + ct * 16 + q * 4 + r;
                float* orow = ob + (size_t)c * NN + i_base;
                #pragma unroll
                for (int it = 0; it < 4; ++it)
                    orow[it * 16 + l15] = o[ct][it][r] * linv[it];
            }
    } else {
        if (l15 == 0) {
            float* lg = (hf == 0) ? l0g : l1g;
            #pragma unroll
            for (int r = 0; r < 4; ++r)
                lg[(size_t)b * NN + i_base + w * 16 + q * 4 + r] = lpart[r];
        }
        if (hf == 0) {
            float* ob = outF + (size_t)b * CC * NN;
            #pragma unroll
            for (int ct = 0; ct < 8; ++ct)
                #pragma unroll
                for (int r = 0; r < 4; ++r) {
                    int c = w * 128 + ct * 16 + q * 4 + r;
                    float* orow = ob + (size_t)c * NN + i_base;
                    #pragma unroll
                    for (int it = 0; it < 4; ++it)
                        orow[it * 16 + l15] = o[ct][it][r];       // unnormalized
                }
        } else {
            u16* ob = outH + (size_t)b * CC * NN;
            #pragma unroll
            for (int ct = 0; ct < 8; ++ct)
                #pragma unroll
                for (int r = 0; r < 4; ++r) {
                    int c = w * 128 + ct * 16 + q * 4 + r;
                    u16* orow = ob + (size_t)c * NN + i_base;
                    #pragma unroll
                    for (int it = 0; it < 4; ++it)
                        orow[it * 16 + l15] = f2b(o[ct][it][r]);
                }
        }
    }
}

// combine: out = (O0 + O1) / (l0 + l1)   (same static M across splits)
__global__ __launch_bounds__(256) void combine_kernel(float* __restrict__ out,
                                                      const u16* __restrict__ P1,
                                                      const float* __restrict__ l0,
                                                      const float* __restrict__ l1) {
    size_t g = (size_t)blockIdx.x * 256 + threadIdx.x;
    size_t f = g * 4;
    int i = (int)(f & (NN - 1));
    int b = (int)(f >> 21);
    float4 p0 = *(float4*)&out[f];
    u64 pk = *(const u64*)&P1[f];
    float p0a[4] = {p0.x, p0.y, p0.z, p0.w};
    float r[4];
    #pragma unroll
    for (int k = 0; k < 4; ++k) {
        float l = l0[(size_t)b * NN + i + k] + l1[(size_t)b * NN + i + k];
        float p1f = b2f((u16)((pk >> (16 * k)) & 0xFFFFu));
        r[k] = (p0a[k] + p1f) / l;
    }
    *(float4*)&out[f] = (float4){r[0], r[1], r[2], r[3]};
}

extern "C" void kernel_launch(void* const* d_in, const int* in_sizes, int n_in,
                              void* d_out, int out_size, void* d_ws, size_t ws_size,
                              hipStream_t stream) {
    const float* x = (const float*)d_in[0];
    size_t SZ = (size_t)BB * NN * CC;          // elements
    u16* XT = (u16*)d_ws;
    u16* XN = XT + SZ;
    u16* P1 = XN + SZ;
    float* norms = (float*)(P1 + SZ);
    float* l0g   = norms + (size_t)BB * NN;
    float* l1g   = l0g + (size_t)BB * NN;
    float* maxn  = l1g + (size_t)BB * NN;
    size_t needed = 3 * SZ * 2 + 3 * (size_t)BB * NN * 4 + 64;
    int split = (ws_size >= needed) ? 1 : 0;
    float* out = (float*)d_out;
    if (!split) {   // fallback layout without P1
        norms = (float*)(XN + SZ);
        l0g = norms + (size_t)BB * NN;
        l1g = l0g;
        maxn = l1g + (size_t)BB * NN;
    }

    hipMemsetAsync(norms, 0, (size_t)BB * NN * sizeof(float), stream);
    prep_kernel<<<2048, 256, 0, stream>>>(x, XT, XN, norms);
    maxn_kernel<<<BB, 256, 0, stream>>>(norms, maxn);
    if (split) {
        flash_kernel<<<512, 256, 0, stream>>>(XT, XN, norms, maxn, out, P1, l0g, l1g, 1);
        combine_kernel<<<(BB * CC * NN / 4) / 256, 256, 0, stream>>>(out, P1, l0g, l1g);
    } else {
        flash_kernel<<<256, 256, 0, stream>>>(XT, XN, norms, maxn, out, P1, l0g, l1g, 0);
    }
}